// Round 8
// baseline (347.499 us; speedup 1.0000x reference)
//
#include <hip/hip_runtime.h>
#include <hip/hip_bf16.h>
#include <math.h>

#define GLOBAL_AS __attribute__((address_space(1)))
#define LDS_AS __attribute__((address_space(3)))

typedef __bf16 bf16x8 __attribute__((ext_vector_type(8)));
typedef float f32x4 __attribute__((ext_vector_type(4)));

#define N 8192
#define D 1024

__device__ __forceinline__ unsigned short f2bf_rne(float f) {
  unsigned u = __float_as_uint(f);
  unsigned r = u + 0x7FFFu + ((u >> 16) & 1u);
  return (unsigned short)(r >> 16);
}

// Convert z (fp32) -> z_hi + z_lo (bf16 split), and row sums of squares.
// zh and zl are adjacent: zl = zh + N*D, forming a [N][2048] "extended" bf16
// matrix whose gram = hi.hi + hi.lo + lo.hi + lo.lo ~= fp32 gram.
__global__ __launch_bounds__(256) void prep_kernel(
    const float* __restrict__ z, unsigned short* __restrict__ zh,
    unsigned short* __restrict__ zl, float* __restrict__ sq) {
  const int r = blockIdx.x, t = threadIdx.x;
  const float4 v = *(const float4*)(z + (size_t)r * D + t * 4);
  float f[4] = {v.x, v.y, v.z, v.w};
  unsigned short hh[4], ll[4];
  float s = 0.f;
#pragma unroll
  for (int u = 0; u < 4; ++u) {
    float x = f[u];
    s = fmaf(x, x, s);
    unsigned short hb = f2bf_rne(x);
    float hf = __uint_as_float(((unsigned)hb) << 16);
    hh[u] = hb;
    ll[u] = f2bf_rne(x - hf);
  }
  *(ushort4*)(zh + (size_t)r * D + t * 4) = make_ushort4(hh[0], hh[1], hh[2], hh[3]);
  *(ushort4*)(zl + (size_t)r * D + t * 4) = make_ushort4(ll[0], ll[1], ll[2], ll[3]);
#pragma unroll
  for (int o = 32; o >= 1; o >>= 1) s += __shfl_down(s, o, 64);
  __shared__ float red[4];
  const int lane = t & 63, wv = t >> 6;
  if (lane == 0) red[wv] = s;
  __syncthreads();
  if (t == 0) sq[r] = ((red[0] + red[1]) + red[2]) + red[3];
}

// ---------------- 256x256-tile 8-phase gram over Kext=2048 ----------------
// 8 waves (2M x 4N), BK=64, 2 K-tiles/iteration, LDS 2 x 64KB K-tile bufs.
// Chunk = one global_load_lds inst = 8KB = 64 rows x 64 cols.
//   A-chunks 0..3 (tile rows c*64..), B-chunks 4..7. buf0 = even tiles,
//   buf1 = odd tiles (fixed roles). Phases 1-4 compute buf0 (qm,kc) =
//   (0,0),(0,1),(1,0),(1,1); phases 5-8 same on buf1.
// Staging (2 chunks/phase, 16/iter = 2 K-tiles): writes of each phase are
// disjoint from that phase's reads; earlier phases are sealed by the
// per-phase trailing barrier. Counted vmcnt at ph4(4)/ph6(6)/ph8(2) - never
// 0 in the main loop; each wave waits for ITS slices, barrier makes it
// collective.
// Swizzle (measured 0-conflict in r1-r7): LDS unit (row,cs) holds global
// unit cs^(row&7); read unit = (kc*4+kg)^(r0&7) -> kc flips byte bit6.
#define WVM(NN) asm volatile("s_waitcnt vmcnt(" #NN ")" ::: "memory")
#define NOOP ((void)0)

#define STG(BUF, CH, TOFFV)                                                          \
  __builtin_amdgcn_global_load_lds(                                                  \
      (const GLOBAL_AS void*)((((CH) < 4) ? aBase + (CH) * 131072                    \
                                          : bBase + ((CH) - 4) * 131072) +           \
                              (TOFFV) + vstage),                                     \
      (LDS_AS void*)(ldsc + (BUF) * 65536 + (CH) * 8192 + tid * 16), 16, 0, 0)

#define MF(MM, AA, NN, BB) \
  acc[MM][NN] = __builtin_amdgcn_mfma_f32_16x16x32_bf16(AA, BB, acc[MM][NN], 0, 0, 0)

#define PH(BUFOFF, QM, KC, STAGES, WAITS)                        \
  {                                                              \
    const char* Ab_ = ldsc + (BUFOFF) + Aw + (QM) * 8192;        \
    const char* Bb_ = ldsc + (BUFOFF) + Bw;                      \
    const unsigned ro_ = arow ^ ((KC) * 64u);                    \
    bf16x8 a0_ = *(const bf16x8*)(Ab_ + ro_);                    \
    bf16x8 a1_ = *(const bf16x8*)(Ab_ + 2048 + ro_);             \
    bf16x8 a2_ = *(const bf16x8*)(Ab_ + 4096 + ro_);             \
    bf16x8 a3_ = *(const bf16x8*)(Ab_ + 6144 + ro_);             \
    bf16x8 b0_ = *(const bf16x8*)(Bb_ + ro_);                    \
    bf16x8 b1_ = *(const bf16x8*)(Bb_ + 2048 + ro_);             \
    bf16x8 b2_ = *(const bf16x8*)(Bb_ + 4096 + ro_);             \
    bf16x8 b3_ = *(const bf16x8*)(Bb_ + 6144 + ro_);             \
    STAGES;                                                      \
    WAITS;                                                       \
    __builtin_amdgcn_s_barrier();                                \
    __builtin_amdgcn_s_setprio(1);                               \
    MF((QM) * 4 + 0, a0_, 0, b0_); MF((QM) * 4 + 0, a0_, 1, b1_);\
    MF((QM) * 4 + 0, a0_, 2, b2_); MF((QM) * 4 + 0, a0_, 3, b3_);\
    MF((QM) * 4 + 1, a1_, 0, b0_); MF((QM) * 4 + 1, a1_, 1, b1_);\
    MF((QM) * 4 + 1, a1_, 2, b2_); MF((QM) * 4 + 1, a1_, 3, b3_);\
    MF((QM) * 4 + 2, a2_, 0, b0_); MF((QM) * 4 + 2, a2_, 1, b1_);\
    MF((QM) * 4 + 2, a2_, 2, b2_); MF((QM) * 4 + 2, a2_, 3, b3_);\
    MF((QM) * 4 + 3, a3_, 0, b0_); MF((QM) * 4 + 3, a3_, 1, b1_);\
    MF((QM) * 4 + 3, a3_, 2, b2_); MF((QM) * 4 + 3, a3_, 3, b3_);\
    __builtin_amdgcn_s_setprio(0);                               \
    __builtin_amdgcn_s_barrier();                                \
  }

__global__ __launch_bounds__(512, 2) void gram_kernel(
    const unsigned short* __restrict__ zh,
    const float* __restrict__ sq, const int* __restrict__ idx,
    float* __restrict__ Pws, float* __restrict__ Pz, float* __restrict__ Ppl) {
  __shared__ __align__(16) char ldsall[131072 + 3072 + 128];
  char* ldsc = ldsall;
  float* comb = (float*)(ldsall + 131072);          // [wc][n][r0][3] cross-wave combine
  float2* lut = (float2*)(ldsall + 131072 + 3072);  // 12 entries

  // XCD-bijective chunked swizzle (528 % 8 == 0)
  int bid = (int)blockIdx.x;
  bid = (bid & 7) * 66 + (bid >> 3);
  // triangle decode: bid = ib*(ib+1)/2 + jb, jb <= ib, ib < 32
  int ibv = (int)((sqrtf(8.f * (float)bid + 1.f) - 1.f) * 0.5f);
  while ((ibv + 1) * (ibv + 2) / 2 <= bid) ++ibv;
  while (ibv * (ibv + 1) / 2 > bid) --ibv;
  const int ib = __builtin_amdgcn_readfirstlane(ibv);
  const int jb = __builtin_amdgcn_readfirstlane(bid - ibv * (ibv + 1) / 2);

  const int tid = threadIdx.x;
  const int lane = tid & 63, wv = tid >> 6;  // 8 waves
  const int wr = wv >> 2, wc = wv & 3;       // 2(M) x 4(N)
  const int r0 = lane & 15, kg = lane >> 4;

  if (tid < 12) {
    const float Pl = (tid == 11) ? 0.f : -2.f * exp2f(-1.5849625007211562f * (float)tid);
    const float w = exp2f(1.4426950408889634f * Pl);
    lut[tid] = make_float2(w, w * Pl);
  }

  // staging: thread t covers chunk-row (t>>3), unit-col (t&7), src unit pre-swizzled
  const unsigned vstage =
      ((unsigned)(tid >> 3) * 2048u) + ((unsigned)((tid & 7) ^ ((tid >> 3) & 7)) * 16u);
  const char* aBase = (const char*)zh + (size_t)ib * 256 * 2048;
  const char* bBase = (const char*)zh + (size_t)jb * 256 * 2048;
  const size_t SEGOFF = (size_t)N * D * 2;  // hi-half -> lo-half byte offset
#define TOFF(T) ((size_t)((T) >> 4) * SEGOFF + (unsigned)(((T) & 15) * 128))

  // LDS read bases: row-in-chunk = (m' or n)*16 + r0; unit = (kc*4+kg)^(r0&7)
  const unsigned arow = (unsigned)(r0 * 128 + ((kg ^ (r0 & 7)) * 16));
  const unsigned Aw = (unsigned)(wr * 2) * 8192u;
  const unsigned Bw = 32768u + (unsigned)wc * 8192u;

  f32x4 acc[8][4];
  const f32x4 vz = {0.f, 0.f, 0.f, 0.f};
#pragma unroll
  for (int m = 0; m < 8; ++m)
#pragma unroll
    for (int n = 0; n < 4; ++n) acc[m][n] = vz;

  // ---- prologue: tile0 -> buf0 (8 chunks), tile1 A0,A2 -> buf1 ----
  {
    const size_t o0 = 0, o1 = TOFF(1);
    STG(0, 0, o0); STG(0, 1, o0); STG(0, 2, o0); STG(0, 3, o0);
    STG(0, 4, o0); STG(0, 5, o0); STG(0, 6, o0); STG(0, 7, o0);
    STG(1, 0, o1); STG(1, 2, o1);
    WVM(2);
    __builtin_amdgcn_s_barrier();
  }

#pragma unroll 1
  for (int i = 0; i < 15; ++i) {
    const size_t o1 = TOFF(2 * i + 1), o2 = TOFF(2 * i + 2), o3 = TOFF(2 * i + 3);
    PH(0,     0, 0, { STG(1, 4, o1); STG(1, 5, o1); }, NOOP);    // ph1
    PH(0,     0, 1, { STG(1, 6, o1); STG(1, 7, o1); }, NOOP);    // ph2
    PH(0,     1, 0, { STG(1, 1, o1); STG(1, 3, o1); }, NOOP);    // ph3
    PH(0,     1, 1, { STG(0, 0, o2); STG(0, 2, o2); }, WVM(4));  // ph4
    PH(65536, 0, 0, { STG(0, 1, o2); STG(0, 3, o2); }, NOOP);    // ph5
    PH(65536, 0, 1, { STG(0, 4, o2); STG(0, 5, o2); }, WVM(6));  // ph6
    PH(65536, 1, 0, { STG(0, 6, o2); STG(0, 7, o2); }, NOOP);    // ph7
    PH(65536, 1, 1, { STG(1, 0, o3); STG(1, 2, o3); }, WVM(2));  // ph8
  }
  {  // peeled final iteration: tiles 30 (buf0) & 31 (buf1), no forward staging
    const size_t o1 = TOFF(31);
    PH(0,     0, 0, { STG(1, 4, o1); STG(1, 5, o1); }, NOOP);
    PH(0,     0, 1, { STG(1, 6, o1); STG(1, 7, o1); }, NOOP);
    PH(0,     1, 0, { STG(1, 1, o1); STG(1, 3, o1); }, NOOP);
    PH(0,     1, 1, NOOP, WVM(0));
    PH(65536, 0, 0, NOOP, NOOP);
    PH(65536, 0, 1, NOOP, NOOP);
    PH(65536, 1, 0, NOOP, NOOP);
    PH(65536, 1, 1, NOOP, NOOP);
  }

  // ---- Epilogue: S = -2*sqrt(max(sq_i+sq_j-2g,0)); padic LUT; partials ----
  const int ibase = ib * 256 + wr * 128 + kg * 4;
  const int jbase = jb * 256 + wc * 64 + r0;
  float sqj[4];
  int idxj[4];
#pragma unroll
  for (int n = 0; n < 4; ++n) {
    sqj[n] = sq[jbase + n * 16];
    idxj[n] = idx[jbase + n * 16];
  }
  const int dslot = jb * 4 + wc;
  float cws[4] = {0.f, 0.f, 0.f, 0.f};
  float czz[4] = {0.f, 0.f, 0.f, 0.f};
  float cpl[4] = {0.f, 0.f, 0.f, 0.f};
#pragma unroll
  for (int m = 0; m < 8; ++m) {
#pragma unroll
    for (int q = 0; q < 4; ++q) {
      const int i = ibase + m * 16 + q;
      const float sqi = sq[i];
      const int idxi = idx[i];
      float ws = 0.f, zz = 0.f, wpl = 0.f;
#pragma unroll
      for (int n = 0; n < 4; ++n) {
        const int j = jbase + n * 16;
        const float g = acc[m][n][q];
        const float d2 = sqi + sqj[n] - 2.f * g;
        const float dd = sqrtf(fmaxf(d2, 0.f));
        const float S = (i == j) ? 0.f : -2.f * dd;
        const int di = idxi - idxj[n];
        const unsigned diff = (unsigned)(di < 0 ? -di : di);
        // v3 via modular-inverse divisibility: /243(+5), /27(+3), /3(+1), /3(+1)
        unsigned dq = diff, qq;
        int vv = 0;
        qq = dq * 3534952507u; { const bool b = qq <= 17674762u;   dq = b ? qq : dq; vv += b ? 5 : 0; }
        qq = dq * 1749801491u; { const bool b = qq <= 159072862u;  dq = b ? qq : dq; vv += b ? 3 : 0; }
        qq = dq * 2863311531u; { const bool b = qq <= 1431655765u; dq = b ? qq : dq; vv += b ? 1 : 0; }
        qq = dq * 2863311531u; { const bool b = qq <= 1431655765u; vv += b ? 1 : 0; }
        vv = (diff == 0u) ? 11 : vv;
        const float2 wt = lut[vv];
        const float wS = wt.x * S;
        ws += wS; zz += wt.x; wpl += wt.y;
        cws[n] += wS; czz[n] += wt.x; cpl[n] += wt.y;
      }
#pragma unroll
      for (int o = 1; o < 16; o <<= 1) {
        ws += __shfl_xor(ws, o, 64);
        zz += __shfl_xor(zz, o, 64);
        wpl += __shfl_xor(wpl, o, 64);
      }
      if (r0 == 0) {
        Pws[(size_t)dslot * N + i] = ws;
        Pz[(size_t)dslot * N + i] = zz;
        Ppl[(size_t)dslot * N + i] = wpl;
      }
    }
  }
  // transposed (column) partials -> rows of block jb, slot ib*4+wc.
  // Reduce over kg in-wave, then combine wr=0 + wr=1 via LDS.
  if (ib != jb) {
    float ta[4], tb[4], tc[4];
#pragma unroll
    for (int n = 0; n < 4; ++n) {
      float a = cws[n], b = czz[n], c = cpl[n];
#pragma unroll
      for (int o = 16; o < 64; o <<= 1) {
        a += __shfl_xor(a, o, 64);
        b += __shfl_xor(b, o, 64);
        c += __shfl_xor(c, o, 64);
      }
      ta[n] = a; tb[n] = b; tc[n] = c;
    }
    if (wr == 1 && kg == 0) {
#pragma unroll
      for (int n = 0; n < 4; ++n) {
        float* p = comb + ((wc * 4 + n) * 16 + r0) * 3;
        p[0] = ta[n]; p[1] = tb[n]; p[2] = tc[n];
      }
    }
    __syncthreads();
    if (wr == 0 && kg == 0) {
      const int tslot = ib * 4 + wc;
#pragma unroll
      for (int n = 0; n < 4; ++n) {
        const float* p = comb + ((wc * 4 + n) * 16 + r0) * 3;
        const int j = jbase + n * 16;
        Pws[(size_t)tslot * N + j] = ta[n] + p[0];
        Pz[(size_t)tslot * N + j] = tb[n] + p[1];
        Ppl[(size_t)tslot * N + j] = tc[n] + p[2];
      }
    }
  }
}

// Per-row: combine the 128 j-partials (fixed order) -> T_i
__global__ __launch_bounds__(256) void r1_kernel(
    const float* __restrict__ Pws, const float* __restrict__ Pz,
    const float* __restrict__ Ppl, float* __restrict__ t) {
  const int row = blockIdx.x * 256 + threadIdx.x;
  float ws = 0.f, zz = 0.f, wpl = 0.f;
  for (int s = 0; s < 128; ++s) {
    ws += Pws[(size_t)s * N + row];
    zz += Pz[(size_t)s * N + row];
    wpl += Ppl[(size_t)s * N + row];
  }
  t[row] = (wpl - ws) / zz - logf(zz);
}

// Final deterministic scalar reduction.
__global__ __launch_bounds__(256) void r2_kernel(const float* __restrict__ t,
                                                 float* __restrict__ out) {
  __shared__ float red[256];
  float s = 0.f;
  for (int r = threadIdx.x; r < N; r += 256) s += t[r];
  red[threadIdx.x] = s;
  __syncthreads();
  for (int o = 128; o > 0; o >>= 1) {
    if (threadIdx.x < (unsigned)o) red[threadIdx.x] += red[threadIdx.x + o];
    __syncthreads();
  }
  if (threadIdx.x == 0) out[0] = red[0] / (float)N;
}

extern "C" void kernel_launch(void* const* d_in, const int* in_sizes, int n_in,
                              void* d_out, int out_size, void* d_ws, size_t ws_size,
                              hipStream_t stream) {
  const float* z = (const float*)d_in[0];
  const int* idx = (const int*)d_in[1];
  float* out = (float*)d_out;
  char* ws = (char*)d_ws;
  // workspace layout (~44.2 MB total); zh and zl MUST be adjacent (Kext view)
  unsigned short* zh = (unsigned short*)ws;                            // 16 MB
  unsigned short* zl = zh + (size_t)N * D;                             // 16 MB
  float* sq = (float*)(ws + ((size_t)32 << 20));                       // 32 KB
  float* Pws = (float*)(ws + ((size_t)32 << 20) + ((size_t)64 << 10)); // 4 MB
  float* Pz = Pws + (size_t)128 * N;                                   // 4 MB
  float* Ppl = Pz + (size_t)128 * N;                                   // 4 MB
  float* tt = Ppl + (size_t)128 * N;                                   // 32 KB

  prep_kernel<<<N, 256, 0, stream>>>(z, zh, zl, sq);
  gram_kernel<<<528, 512, 0, stream>>>(zh, sq, idx, Pws, Pz, Ppl);
  r1_kernel<<<N / 256, 256, 0, stream>>>(Pws, Pz, Ppl, tt);
  r2_kernel<<<1, 256, 0, stream>>>(tt, out);
}

// Round 9
// 346.754 us; speedup vs baseline: 1.0021x; 1.0021x over previous
//
#include <hip/hip_runtime.h>
#include <hip/hip_bf16.h>
#include <math.h>

#define GLOBAL_AS __attribute__((address_space(1)))
#define LDS_AS __attribute__((address_space(3)))

typedef __bf16 bf16x8 __attribute__((ext_vector_type(8)));
typedef float f32x4 __attribute__((ext_vector_type(4)));

#define N 8192
#define D 1024

__device__ __forceinline__ unsigned short f2bf_rne(float f) {
  unsigned u = __float_as_uint(f);
  unsigned r = u + 0x7FFFu + ((u >> 16) & 1u);
  return (unsigned short)(r >> 16);
}

// Convert z (fp32) -> z_hi + z_lo (bf16 split), and row sums of squares.
// zh and zl are adjacent: zl = zh + N*D, forming a [N][2048] "extended" bf16
// matrix whose gram = hi.hi + hi.lo + lo.hi + lo.lo ~= fp32 gram.
__global__ __launch_bounds__(256) void prep_kernel(
    const float* __restrict__ z, unsigned short* __restrict__ zh,
    unsigned short* __restrict__ zl, float* __restrict__ sq) {
  const int r = blockIdx.x, t = threadIdx.x;
  const float4 v = *(const float4*)(z + (size_t)r * D + t * 4);
  float f[4] = {v.x, v.y, v.z, v.w};
  unsigned short hh[4], ll[4];
  float s = 0.f;
#pragma unroll
  for (int u = 0; u < 4; ++u) {
    float x = f[u];
    s = fmaf(x, x, s);
    unsigned short hb = f2bf_rne(x);
    float hf = __uint_as_float(((unsigned)hb) << 16);
    hh[u] = hb;
    ll[u] = f2bf_rne(x - hf);
  }
  *(ushort4*)(zh + (size_t)r * D + t * 4) = make_ushort4(hh[0], hh[1], hh[2], hh[3]);
  *(ushort4*)(zl + (size_t)r * D + t * 4) = make_ushort4(ll[0], ll[1], ll[2], ll[3]);
#pragma unroll
  for (int o = 32; o >= 1; o >>= 1) s += __shfl_down(s, o, 64);
  __shared__ float red[4];
  const int lane = t & 63, wv = t >> 6;
  if (lane == 0) red[wv] = s;
  __syncthreads();
  if (t == 0) sq[r] = ((red[0] + red[1]) + red[2]) + red[3];
}

// ---------------- 256x256-tile 8-phase gram over Kext=2048 ----------------
// 8 waves (2M x 4N), BK=64, 2 K-tiles/iteration, LDS 2 x 64KB K-tile bufs.
// Chunk = one global_load_lds inst = 8KB = 64 rows x 64 cols.
//   A-chunks 0..3 (tile rows c*64..), B-chunks 4..7. buf0 = even tiles,
//   buf1 = odd tiles (fixed roles). Phases 1-4 compute buf0 (qm,kc) =
//   (0,0),(0,1),(1,0),(1,1); phases 5-8 same on buf1.
// Staging (2 chunks/phase, 16/iter = 2 K-tiles): writes of each phase are
// disjoint from that phase's reads; earlier phases are sealed by the
// per-phase trailing barrier. Counted vmcnt at ph4(4)/ph6(6)/ph8(2) - never
// 0 in the main loop.
// Swizzle (measured 0-conflict in r1-r7): LDS unit (row,cs) holds global
// unit cs^(row&7); read unit = (kc*4+kg)^(r0&7) -> kc flips byte bit6.
//
// launch_bounds(512,1): LDS (134.7KB) already limits to 1 block/CU, so a
// reg cap buys NOTHING. r8's (512,2) = 256-reg cap vs a ~300-reg live set
// (128 AGPR acc + frags + staging) -> 170MB scratch spill, MfmaUtil 17%.
// Lesson (4th time): never cap below the live set.
#define WVM(NN) asm volatile("s_waitcnt vmcnt(" #NN ")" ::: "memory")
#define NOOP ((void)0)

#define STG(BUF, CH, TOFFV)                                                          \
  __builtin_amdgcn_global_load_lds(                                                  \
      (const GLOBAL_AS void*)((((CH) < 4) ? aBase + (CH) * 131072                    \
                                          : bBase + ((CH) - 4) * 131072) +           \
                              (TOFFV) + vstage),                                     \
      (LDS_AS void*)(ldsc + (BUF) * 65536 + (CH) * 8192 + tid * 16), 16, 0, 0)

#define MF(MM, AA, NN, BB) \
  acc[MM][NN] = __builtin_amdgcn_mfma_f32_16x16x32_bf16(AA, BB, acc[MM][NN], 0, 0, 0)

#define PH(BUFOFF, QM, KC, STAGES, WAITS)                        \
  {                                                              \
    const char* Ab_ = ldsc + (BUFOFF) + Aw + (QM) * 8192;        \
    const char* Bb_ = ldsc + (BUFOFF) + Bw;                      \
    const unsigned ro_ = arow ^ ((KC) * 64u);                    \
    bf16x8 a0_ = *(const bf16x8*)(Ab_ + ro_);                    \
    bf16x8 a1_ = *(const bf16x8*)(Ab_ + 2048 + ro_);             \
    bf16x8 a2_ = *(const bf16x8*)(Ab_ + 4096 + ro_);             \
    bf16x8 a3_ = *(const bf16x8*)(Ab_ + 6144 + ro_);             \
    bf16x8 b0_ = *(const bf16x8*)(Bb_ + ro_);                    \
    bf16x8 b1_ = *(const bf16x8*)(Bb_ + 2048 + ro_);             \
    bf16x8 b2_ = *(const bf16x8*)(Bb_ + 4096 + ro_);             \
    bf16x8 b3_ = *(const bf16x8*)(Bb_ + 6144 + ro_);             \
    STAGES;                                                      \
    WAITS;                                                       \
    __builtin_amdgcn_s_barrier();                                \
    __builtin_amdgcn_s_setprio(1);                               \
    MF((QM) * 4 + 0, a0_, 0, b0_); MF((QM) * 4 + 0, a0_, 1, b1_);\
    MF((QM) * 4 + 0, a0_, 2, b2_); MF((QM) * 4 + 0, a0_, 3, b3_);\
    MF((QM) * 4 + 1, a1_, 0, b0_); MF((QM) * 4 + 1, a1_, 1, b1_);\
    MF((QM) * 4 + 1, a1_, 2, b2_); MF((QM) * 4 + 1, a1_, 3, b3_);\
    MF((QM) * 4 + 2, a2_, 0, b0_); MF((QM) * 4 + 2, a2_, 1, b1_);\
    MF((QM) * 4 + 2, a2_, 2, b2_); MF((QM) * 4 + 2, a2_, 3, b3_);\
    MF((QM) * 4 + 3, a3_, 0, b0_); MF((QM) * 4 + 3, a3_, 1, b1_);\
    MF((QM) * 4 + 3, a3_, 2, b2_); MF((QM) * 4 + 3, a3_, 3, b3_);\
    __builtin_amdgcn_s_setprio(0);                               \
    __builtin_amdgcn_s_barrier();                                \
  }

__global__ __launch_bounds__(512, 1) void gram_kernel(
    const unsigned short* __restrict__ zh,
    const float* __restrict__ sq, const int* __restrict__ idx,
    float* __restrict__ Pws, float* __restrict__ Pz, float* __restrict__ Ppl) {
  __shared__ __align__(16) char ldsall[131072 + 3072 + 128];
  char* ldsc = ldsall;
  float* comb = (float*)(ldsall + 131072);          // [wc][n][r0][3] cross-wave combine
  float2* lut = (float2*)(ldsall + 131072 + 3072);  // 12 entries

  // XCD-bijective chunked swizzle (528 % 8 == 0)
  int bid = (int)blockIdx.x;
  bid = (bid & 7) * 66 + (bid >> 3);
  // triangle decode: bid = ib*(ib+1)/2 + jb, jb <= ib, ib < 32
  int ibv = (int)((sqrtf(8.f * (float)bid + 1.f) - 1.f) * 0.5f);
  while ((ibv + 1) * (ibv + 2) / 2 <= bid) ++ibv;
  while (ibv * (ibv + 1) / 2 > bid) --ibv;
  const int ib = __builtin_amdgcn_readfirstlane(ibv);
  const int jb = __builtin_amdgcn_readfirstlane(bid - ibv * (ibv + 1) / 2);

  const int tid = threadIdx.x;
  const int lane = tid & 63, wv = tid >> 6;  // 8 waves
  const int wr = wv >> 2, wc = wv & 3;       // 2(M) x 4(N)
  const int r0 = lane & 15, kg = lane >> 4;

  if (tid < 12) {
    const float Pl = (tid == 11) ? 0.f : -2.f * exp2f(-1.5849625007211562f * (float)tid);
    const float w = exp2f(1.4426950408889634f * Pl);
    lut[tid] = make_float2(w, w * Pl);
  }

  // staging: thread t covers chunk-row (t>>3), unit-col (t&7), src unit pre-swizzled
  const unsigned vstage =
      ((unsigned)(tid >> 3) * 2048u) + ((unsigned)((tid & 7) ^ ((tid >> 3) & 7)) * 16u);
  const char* aBase = (const char*)zh + (size_t)ib * 256 * 2048;
  const char* bBase = (const char*)zh + (size_t)jb * 256 * 2048;
  const size_t SEGOFF = (size_t)N * D * 2;  // hi-half -> lo-half byte offset
#define TOFF(T) ((size_t)((T) >> 4) * SEGOFF + (unsigned)(((T) & 15) * 128))

  // LDS read bases: row-in-chunk = (m' or n)*16 + r0; unit = (kc*4+kg)^(r0&7)
  const unsigned arow = (unsigned)(r0 * 128 + ((kg ^ (r0 & 7)) * 16));
  const unsigned Aw = (unsigned)(wr * 2) * 8192u;
  const unsigned Bw = 32768u + (unsigned)wc * 8192u;

  f32x4 acc[8][4];
  const f32x4 vz = {0.f, 0.f, 0.f, 0.f};
#pragma unroll
  for (int m = 0; m < 8; ++m)
#pragma unroll
    for (int n = 0; n < 4; ++n) acc[m][n] = vz;

  // ---- prologue: tile0 -> buf0 (8 chunks), tile1 A0,A2 -> buf1 ----
  {
    const size_t o0 = 0, o1 = TOFF(1);
    STG(0, 0, o0); STG(0, 1, o0); STG(0, 2, o0); STG(0, 3, o0);
    STG(0, 4, o0); STG(0, 5, o0); STG(0, 6, o0); STG(0, 7, o0);
    STG(1, 0, o1); STG(1, 2, o1);
    WVM(2);
    __builtin_amdgcn_s_barrier();
  }

#pragma unroll 1
  for (int i = 0; i < 15; ++i) {
    const size_t o1 = TOFF(2 * i + 1), o2 = TOFF(2 * i + 2), o3 = TOFF(2 * i + 3);
    PH(0,     0, 0, { STG(1, 4, o1); STG(1, 5, o1); }, NOOP);    // ph1
    PH(0,     0, 1, { STG(1, 6, o1); STG(1, 7, o1); }, NOOP);    // ph2
    PH(0,     1, 0, { STG(1, 1, o1); STG(1, 3, o1); }, NOOP);    // ph3
    PH(0,     1, 1, { STG(0, 0, o2); STG(0, 2, o2); }, WVM(4));  // ph4
    PH(65536, 0, 0, { STG(0, 1, o2); STG(0, 3, o2); }, NOOP);    // ph5
    PH(65536, 0, 1, { STG(0, 4, o2); STG(0, 5, o2); }, WVM(6));  // ph6
    PH(65536, 1, 0, { STG(0, 6, o2); STG(0, 7, o2); }, NOOP);    // ph7
    PH(65536, 1, 1, { STG(1, 0, o3); STG(1, 2, o3); }, WVM(2));  // ph8
  }
  {  // peeled final iteration: tiles 30 (buf0) & 31 (buf1), no forward staging
    const size_t o1 = TOFF(31);
    PH(0,     0, 0, { STG(1, 4, o1); STG(1, 5, o1); }, NOOP);
    PH(0,     0, 1, { STG(1, 6, o1); STG(1, 7, o1); }, NOOP);
    PH(0,     1, 0, { STG(1, 1, o1); STG(1, 3, o1); }, NOOP);
    PH(0,     1, 1, NOOP, WVM(0));
    PH(65536, 0, 0, NOOP, NOOP);
    PH(65536, 0, 1, NOOP, NOOP);
    PH(65536, 1, 0, NOOP, NOOP);
    PH(65536, 1, 1, NOOP, NOOP);
  }

  // ---- Epilogue: S = -2*sqrt(max(sq_i+sq_j-2g,0)); padic LUT; partials ----
  const int ibase = ib * 256 + wr * 128 + kg * 4;
  const int jbase = jb * 256 + wc * 64 + r0;
  float sqj[4];
  int idxj[4];
#pragma unroll
  for (int n = 0; n < 4; ++n) {
    sqj[n] = sq[jbase + n * 16];
    idxj[n] = idx[jbase + n * 16];
  }
  const int dslot = jb * 4 + wc;
  float cws[4] = {0.f, 0.f, 0.f, 0.f};
  float czz[4] = {0.f, 0.f, 0.f, 0.f};
  float cpl[4] = {0.f, 0.f, 0.f, 0.f};
#pragma unroll
  for (int m = 0; m < 8; ++m) {
#pragma unroll
    for (int q = 0; q < 4; ++q) {
      const int i = ibase + m * 16 + q;
      const float sqi = sq[i];
      const int idxi = idx[i];
      float ws = 0.f, zz = 0.f, wpl = 0.f;
#pragma unroll
      for (int n = 0; n < 4; ++n) {
        const int j = jbase + n * 16;
        const float g = acc[m][n][q];
        const float d2 = sqi + sqj[n] - 2.f * g;
        const float dd = sqrtf(fmaxf(d2, 0.f));
        const float S = (i == j) ? 0.f : -2.f * dd;
        const int di = idxi - idxj[n];
        const unsigned diff = (unsigned)(di < 0 ? -di : di);
        // v3 via modular-inverse divisibility: /243(+5), /27(+3), /3(+1), /3(+1)
        unsigned dq = diff, qq;
        int vv = 0;
        qq = dq * 3534952507u; { const bool b = qq <= 17674762u;   dq = b ? qq : dq; vv += b ? 5 : 0; }
        qq = dq * 1749801491u; { const bool b = qq <= 159072862u;  dq = b ? qq : dq; vv += b ? 3 : 0; }
        qq = dq * 2863311531u; { const bool b = qq <= 1431655765u; dq = b ? qq : dq; vv += b ? 1 : 0; }
        qq = dq * 2863311531u; { const bool b = qq <= 1431655765u; vv += b ? 1 : 0; }
        vv = (diff == 0u) ? 11 : vv;
        const float2 wt = lut[vv];
        const float wS = wt.x * S;
        ws += wS; zz += wt.x; wpl += wt.y;
        cws[n] += wS; czz[n] += wt.x; cpl[n] += wt.y;
      }
#pragma unroll
      for (int o = 1; o < 16; o <<= 1) {
        ws += __shfl_xor(ws, o, 64);
        zz += __shfl_xor(zz, o, 64);
        wpl += __shfl_xor(wpl, o, 64);
      }
      if (r0 == 0) {
        Pws[(size_t)dslot * N + i] = ws;
        Pz[(size_t)dslot * N + i] = zz;
        Ppl[(size_t)dslot * N + i] = wpl;
      }
    }
  }
  // transposed (column) partials -> rows of block jb, slot ib*4+wc.
  // Reduce over kg in-wave, then combine wr=0 + wr=1 via LDS.
  if (ib != jb) {
    float ta[4], tb[4], tc[4];
#pragma unroll
    for (int n = 0; n < 4; ++n) {
      float a = cws[n], b = czz[n], c = cpl[n];
#pragma unroll
      for (int o = 16; o < 64; o <<= 1) {
        a += __shfl_xor(a, o, 64);
        b += __shfl_xor(b, o, 64);
        c += __shfl_xor(c, o, 64);
      }
      ta[n] = a; tb[n] = b; tc[n] = c;
    }
    if (wr == 1 && kg == 0) {
#pragma unroll
      for (int n = 0; n < 4; ++n) {
        float* p = comb + ((wc * 4 + n) * 16 + r0) * 3;
        p[0] = ta[n]; p[1] = tb[n]; p[2] = tc[n];
      }
    }
    __syncthreads();
    if (wr == 0 && kg == 0) {
      const int tslot = ib * 4 + wc;
#pragma unroll
      for (int n = 0; n < 4; ++n) {
        const float* p = comb + ((wc * 4 + n) * 16 + r0) * 3;
        const int j = jbase + n * 16;
        Pws[(size_t)tslot * N + j] = ta[n] + p[0];
        Pz[(size_t)tslot * N + j] = tb[n] + p[1];
        Ppl[(size_t)tslot * N + j] = tc[n] + p[2];
      }
    }
  }
}

// Per-row: combine the 128 j-partials (fixed order) -> T_i
__global__ __launch_bounds__(256) void r1_kernel(
    const float* __restrict__ Pws, const float* __restrict__ Pz,
    const float* __restrict__ Ppl, float* __restrict__ t) {
  const int row = blockIdx.x * 256 + threadIdx.x;
  float ws = 0.f, zz = 0.f, wpl = 0.f;
  for (int s = 0; s < 128; ++s) {
    ws += Pws[(size_t)s * N + row];
    zz += Pz[(size_t)s * N + row];
    wpl += Ppl[(size_t)s * N + row];
  }
  t[row] = (wpl - ws) / zz - logf(zz);
}

// Final deterministic scalar reduction.
__global__ __launch_bounds__(256) void r2_kernel(const float* __restrict__ t,
                                                 float* __restrict__ out) {
  __shared__ float red[256];
  float s = 0.f;
  for (int r = threadIdx.x; r < N; r += 256) s += t[r];
  red[threadIdx.x] = s;
  __syncthreads();
  for (int o = 128; o > 0; o >>= 1) {
    if (threadIdx.x < (unsigned)o) red[threadIdx.x] += red[threadIdx.x + o];
    __syncthreads();
  }
  if (threadIdx.x == 0) out[0] = red[0] / (float)N;
}

extern "C" void kernel_launch(void* const* d_in, const int* in_sizes, int n_in,
                              void* d_out, int out_size, void* d_ws, size_t ws_size,
                              hipStream_t stream) {
  const float* z = (const float*)d_in[0];
  const int* idx = (const int*)d_in[1];
  float* out = (float*)d_out;
  char* ws = (char*)d_ws;
  // workspace layout (~44.2 MB total); zh and zl MUST be adjacent (Kext view)
  unsigned short* zh = (unsigned short*)ws;                            // 16 MB
  unsigned short* zl = zh + (size_t)N * D;                             // 16 MB
  float* sq = (float*)(ws + ((size_t)32 << 20));                       // 32 KB
  float* Pws = (float*)(ws + ((size_t)32 << 20) + ((size_t)64 << 10)); // 4 MB
  float* Pz = Pws + (size_t)128 * N;                                   // 4 MB
  float* Ppl = Pz + (size_t)128 * N;                                   // 4 MB
  float* tt = Ppl + (size_t)128 * N;                                   // 32 KB

  prep_kernel<<<N, 256, 0, stream>>>(z, zh, zl, sq);
  gram_kernel<<<528, 512, 0, stream>>>(zh, sq, idx, Pws, Pz, Ppl);
  r1_kernel<<<N / 256, 256, 0, stream>>>(Pws, Pz, Ppl, tt);
  r2_kernel<<<1, 256, 0, stream>>>(tt, out);
}